// Round 1
// baseline (275.052 us; speedup 1.0000x reference)
//
#include <hip/hip_runtime.h>
#include <hip/hip_fp16.h>
#include <math.h>

#define BATCH 8
#define N 2048
#define D 128
#define ST 4000

#define TJ 64        // j-tile per K-step
#define IT 16        // i-rows per block (one i-tile, shared by 4 k-quarter waves)
#define KQ 4         // K-quarters = waves per block
#define TPW 8        // tiles per wave = N/TJ/KQ

typedef short bf16x8 __attribute__((ext_vector_type(8)));
typedef float f32x4  __attribute__((ext_vector_type(4)));
typedef unsigned u32x4 __attribute__((ext_vector_type(4)));

__device__ __forceinline__ unsigned short f2bf(float f) {
    union { float f; unsigned u; } v; v.f = f;
    const unsigned r = v.u + 0x7FFFu + ((v.u >> 16) & 1u);   // RNE
    return (unsigned short)(r >> 16);
}

// ---------------------------------------------------------------------------
// Pack kernel: P[r][c] = (bf16(M*exp|W|) << 16) | fp16(exp|W|).
// exp moved here (16M BW-bound evaluations) out of the latency-critical fused
// loop (33.5M). max|W| over 16M N(0,1) samples ~5.8 -> e<=330, fits fp16 with
// 4.9e-4 rel err; bf16(m*e) matches previous numerator precision.
// M/W are pure streams (never reused) -> nontemporal loads so they don't
// evict the freshly written P (64 MB, wanted L3-resident for fused gathers).
// ---------------------------------------------------------------------------
__global__ __launch_bounds__(256) void pack_kernel(
    const float* __restrict__ M, const float* __restrict__ W,
    unsigned* __restrict__ P)
{
    const size_t i4 = ((size_t)blockIdx.x * 256 + threadIdx.x) * 4;
    const f32x4 m4 = __builtin_nontemporal_load((const f32x4*)(M + i4));
    const f32x4 w4 = __builtin_nontemporal_load((const f32x4*)(W + i4));
    u32x4 o;
    {
        const float e = __expf(fabsf(w4.x));
        o.x = ((unsigned)f2bf(m4.x * e) << 16) | (unsigned)__half_as_ushort(__float2half(e));
    }
    {
        const float e = __expf(fabsf(w4.y));
        o.y = ((unsigned)f2bf(m4.y * e) << 16) | (unsigned)__half_as_ushort(__float2half(e));
    }
    {
        const float e = __expf(fabsf(w4.z));
        o.z = ((unsigned)f2bf(m4.z * e) << 16) | (unsigned)__half_as_ushort(__float2half(e));
    }
    {
        const float e = __expf(fabsf(w4.w));
        o.w = ((unsigned)f2bf(m4.w * e) << 16) | (unsigned)__half_as_ushort(__float2half(e));
    }
    *(u32x4*)(P + i4) = o;
}

// ---------------------------------------------------------------------------
// Counting sort per batch (values < 4000). Ties in any order: the matmul is
// invariant to j-permutation.
// ---------------------------------------------------------------------------
__global__ __launch_bounds__(1024) void sort_kernel(
    const int* __restrict__ stk_ten,
    int* __restrict__ sval,
    int* __restrict__ spos)
{
    __shared__ int hist[4000];
    __shared__ int base[4000];
    __shared__ int wsum[16];
    const int b = blockIdx.x, t = threadIdx.x;
    const int lane = t & 63, wv = t >> 6;
    const int* idxb = stk_ten + b * N;

    for (int j = t; j < 4000; j += 1024) hist[j] = 0;
    __syncthreads();
    const int v0 = idxb[t], v1 = idxb[t + 1024];
    atomicAdd(&hist[v0], 1);
    atomicAdd(&hist[v1], 1);
    __syncthreads();

    // scan: thread owns bins 4t..4t+3
    int h[4], c[4], run = 0;
    #pragma unroll
    for (int i = 0; i < 4; ++i) {
        const int bi = 4 * t + i;
        h[i] = (bi < 4000) ? hist[bi] : 0;
        run += h[i];
        c[i] = run;
    }
    const int tsum = run;
    int incl = tsum;
    #pragma unroll
    for (int d = 1; d < 64; d <<= 1) {
        const int tmp = __shfl_up(incl, d, 64);
        if (lane >= d) incl += tmp;
    }
    if (lane == 63) wsum[wv] = incl;
    __syncthreads();
    if (t < 16) {
        const int v = wsum[t];
        int iv = v;
        #pragma unroll
        for (int d = 1; d < 16; d <<= 1) {
            const int tmp = __shfl_up(iv, d, 64);
            if (lane >= d) iv += tmp;
        }
        wsum[t] = iv - v;               // exclusive across waves
    }
    __syncthreads();
    const int ex = incl - tsum + wsum[wv];
    #pragma unroll
    for (int i = 0; i < 4; ++i) {
        const int bi = 4 * t + i;
        if (bi < 4000) base[bi] = ex + c[i] - h[i];
    }
    __syncthreads();
    for (int j = t; j < 4000; j += 1024) hist[j] = 0;
    __syncthreads();
    {
        const int p0 = base[v0] + atomicAdd(&hist[v0], 1);
        sval[b * N + p0] = v0; spos[b * N + p0] = t;
        const int p1 = base[v1] + atomicAdd(&hist[v1], 1);
        sval[b * N + p1] = v1; spos[b * N + p1] = t + 1024;
    }
}

// ---------------------------------------------------------------------------
// xT[b][d][j_sorted] = bf16(x[b][spos[j]][d]).  4 MB, L2-resident B operand.
// ---------------------------------------------------------------------------
__global__ __launch_bounds__(256) void xt_kernel(
    const float* __restrict__ x,
    const int* __restrict__ spos,
    unsigned short* __restrict__ xT)
{
    __shared__ float xs[TJ][129];
    __shared__ int sp_s[TJ];
    const int t  = threadIdx.x;
    const int b  = blockIdx.x >> 5;
    const int jt = blockIdx.x & 31;
    const int j0 = jt * TJ;
    if (t < TJ) sp_s[t] = spos[b * N + j0 + t];
    __syncthreads();
    const int tx = t & 31, ty = t >> 5;
    const float* xb = x + (size_t)b * N * D;
    #pragma unroll
    for (int p = 0; p < 8; ++p) {
        const int r = ty + 8 * p;
        const float* src = xb + (size_t)sp_s[r] * D;
        #pragma unroll
        for (int i = 0; i < 4; ++i)
            xs[r][tx + 32 * i] = src[tx + 32 * i];
    }
    __syncthreads();
    const int jp = t & 31, dd0 = t >> 5;
    unsigned short* xTb = xT + (size_t)b * D * N;
    #pragma unroll
    for (int q = 0; q < 16; ++q) {
        const int dd = dd0 + 8 * q;
        const unsigned lo = f2bf(xs[2 * jp][dd]);
        const unsigned hi = f2bf(xs[2 * jp + 1][dd]);
        *(unsigned*)(xTb + (size_t)dd * N + j0 + 2 * jp) = (hi << 16) | lo;
    }
}

// ---------------------------------------------------------------------------
// Fused kernel, wave-autonomous K-split. Changes this round (occupancy fix):
//  - LDS 43.5KB -> ~18KB: the 34KB accbuf staging replaced by one
//    zero-initialized accs[16][132] reduced with LDS float atomicAdd
//    (epilogue only; stride 132 -> the 4 row-groups land 2-way = free).
//  - __launch_bounds__(256,4): grid is 1024 blocks = exactly 4/CU; occupancy
//    27% -> ~50%, doubling in-flight gather streams (kernel is gather-
//    latency-bound: MfmaUtil 3.7%, HBM 22%).
//  - exp|W| is now precomputed in pack: inner loop per coefficient is
//    unpack-e / l+=e / store high 16 bits (already bf16) to LDS. No expf,
//    no f2bf between the gather-wait and the MFMAs.
//  - XCD swizzle: 8 batches x 128 i-tiles; batch b -> XCD b, so each XCD's
//    L2 holds one xT[b] (512KB) instead of all eight (4MB = entire L2).
// ---------------------------------------------------------------------------
__global__ __launch_bounds__(256, 4) void fused_kernel(
    const unsigned short* __restrict__ xT,
    const int* __restrict__ stk_ten,
    const unsigned* __restrict__ P,
    const int* __restrict__ sval,
    const int* __restrict__ spos,
    float* __restrict__ out)
{
    __shared__ __align__(16) unsigned short cs[KQ][IT * 72]; // 9216 B, per-wave
    __shared__ float accs[IT][132];                          // 8448 B
    __shared__ float lbuf[KQ][IT];
    __shared__ int ri_s[IT];

    const int t    = threadIdx.x;
    const int lane = t & 63;
    const int w    = t >> 6;
    const int wg   = (blockIdx.x & 7) * 128 + (blockIdx.x >> 3);  // batch->XCD
    const int b    = wg >> 7;                    // 128 i-tiles per batch
    const int i0   = (wg & 127) * IT;

    if (t < IT) ri_s[t] = stk_ten[b * N + i0 + t];
    for (int z = t; z < IT * 132; z += 256) (&accs[0][0])[z] = 0.0f;
    __syncthreads();

    unsigned rowoff[IT];
    #pragma unroll
    for (int m = 0; m < IT; ++m) rowoff[m] = (unsigned)ri_s[m] * ST;

    const int* svb = sval + b * N;
    const int* spb = spos + b * N;
    const unsigned short* xTb = xT + (size_t)b * D * N;
    unsigned short* csw = &cs[w][0];

    f32x4 acc[8];
    #pragma unroll
    for (int nb = 0; nb < 8; ++nb)
        #pragma unroll
        for (int r = 0; r < 4; ++r) acc[nb][r] = 0.0f;
    float l_part[IT];
    #pragma unroll
    for (int m = 0; m < IT; ++m) l_part[m] = 0.0f;

    const int jbase = w * (TPW * TJ);
    const int brow  = lane & 15;
    const int bcol  = (lane >> 4) * 8;

    // prologue: tile 0 indices + gathers
    int cj = svb[jbase + lane];
    int pj = spb[jbase + lane];
    unsigned gv[IT];
    #pragma unroll
    for (int m = 0; m < IT; ++m) gv[m] = P[rowoff[m] + (unsigned)cj];

    for (int tt = 0; tt < TPW; ++tt) {
        const int j0  = jbase + tt * TJ;
        const int j0n = (tt == TPW - 1) ? jbase : j0 + TJ;   // clamped, discarded

        // issue next indices, then B(kc=0) — latency overlapped by coef VALU
        const int cjn = svb[j0n + lane];
        const int pjn = spb[j0n + lane];
        uint4 bv[8];
        #pragma unroll
        for (int nb = 0; nb < 8; ++nb)
            bv[nb] = *(const uint4*)(xTb + (size_t)(nb * 16 + brow) * N + j0 + bcol);

        // coefficients for tile tt from prefetched packed gathers:
        // high 16 bits = bf16(m*e) (ready for LDS), low = fp16(e)
        #pragma unroll
        for (int m = 0; m < IT; ++m) {
            const unsigned u = gv[m];
            const float e = __half2float(__ushort_as_half((unsigned short)(u & 0xFFFFu)));
            const bool diag = (pj == i0 + m);
            l_part[m] += diag ? 1.0f : e;
            csw[m * 72 + lane] = diag ? (unsigned short)0 : (unsigned short)(u >> 16);
        }

        // A-fragments (same-wave LDS round-trip; lgkmcnt only, no barrier)
        const bf16x8 av0 = *(const bf16x8*)(csw + brow * 72 + bcol);
        const bf16x8 av1 = *(const bf16x8*)(csw + brow * 72 + 32 + bcol);

        // issue next tile's scattered gathers; land during MFMAs
        unsigned gvn[IT];
        #pragma unroll
        for (int m = 0; m < IT; ++m) gvn[m] = P[rowoff[m] + (unsigned)cjn];

        #pragma unroll
        for (int nb = 0; nb < 8; ++nb)
            acc[nb] = __builtin_amdgcn_mfma_f32_16x16x32_bf16(
                av0, *(const bf16x8*)&bv[nb], acc[nb], 0, 0, 0);
        #pragma unroll
        for (int nb = 0; nb < 8; ++nb)
            bv[nb] = *(const uint4*)(xTb + (size_t)(nb * 16 + brow) * N + j0 + 32 + bcol);
        #pragma unroll
        for (int nb = 0; nb < 8; ++nb)
            acc[nb] = __builtin_amdgcn_mfma_f32_16x16x32_bf16(
                av1, *(const bf16x8*)&bv[nb], acc[nb], 0, 0, 0);

        #pragma unroll
        for (int m = 0; m < IT; ++m) gv[m] = gvn[m];
        cj = cjn; pj = pjn;
    }

    // epilogue: l butterfly (once), acc -> LDS via float atomics, reduce
    #pragma unroll
    for (int m = 0; m < IT; ++m) {
        float v = l_part[m];
        #pragma unroll
        for (int d = 1; d < 64; d <<= 1) v += __shfl_xor(v, d, 64);
        if (lane == 0) lbuf[w][m] = v;
    }
    #pragma unroll
    for (int nb = 0; nb < 8; ++nb)
        #pragma unroll
        for (int r = 0; r < 4; ++r)
            atomicAdd(&accs[(lane >> 4) * 4 + r][nb * 16 + (lane & 15)], acc[nb][r]);
    __syncthreads();

    #pragma unroll
    for (int rr = 0; rr < 4; ++rr) {
        const int row = 4 * w + rr;
        const float linv = 1.0f /
            (lbuf[0][row] + lbuf[1][row] + lbuf[2][row] + lbuf[3][row]);
        #pragma unroll
        for (int p = 0; p < 2; ++p) {
            const int dd = lane + 64 * p;
            out[((size_t)(b * N + i0 + row) << 7) + dd] = accs[row][dd] * linv;
        }
    }
}

extern "C" void kernel_launch(void* const* d_in, const int* in_sizes, int n_in,
                              void* d_out, int out_size, void* d_ws, size_t ws_size,
                              hipStream_t stream) {
    const float* x          = (const float*)d_in[0];
    const int*   stk_ten    = (const int*)d_in[1];
    const float* stk_matrix = (const float*)d_in[2];
    const float* stk_weight = (const float*)d_in[3];
    float* out = (float*)d_out;

    unsigned* P = (unsigned*)d_ws;                              // 64 MB
    int* sval = (int*)(P + (size_t)ST * ST);                    // 64 KB
    int* spos = sval + BATCH * N;                               // 64 KB
    unsigned short* xT = (unsigned short*)(spos + BATCH * N);   // 4 MB

    pack_kernel<<<(ST * ST) / 1024, 256, 0, stream>>>(stk_matrix, stk_weight, P);
    sort_kernel<<<BATCH, 1024, 0, stream>>>(stk_ten, sval, spos);
    xt_kernel<<<BATCH * (N / TJ), 256, 0, stream>>>(x, spos, xT);
    fused_kernel<<<BATCH * (N / IT), 256, 0, stream>>>(
        xT, stk_ten, P, sval, spos, out);
}

// Round 2
// 274.962 us; speedup vs baseline: 1.0003x; 1.0003x over previous
//
#include <hip/hip_runtime.h>
#include <hip/hip_fp16.h>
#include <math.h>

#define BATCH 8
#define N 2048
#define D 128
#define ST 4000

#define TJ 64        // j-tile per K-step
#define IT 16        // i-rows per block (one i-tile, shared by 4 k-quarter waves)
#define KQ 4         // K-quarters = waves per block
#define TPW 8        // tiles per wave = N/TJ/KQ

typedef short bf16x8 __attribute__((ext_vector_type(8)));
typedef float f32x4  __attribute__((ext_vector_type(4)));
typedef unsigned u32x4 __attribute__((ext_vector_type(4)));

__device__ __forceinline__ unsigned short f2bf(float f) {
    union { float f; unsigned u; } v; v.f = f;
    const unsigned r = v.u + 0x7FFFu + ((v.u >> 16) & 1u);   // RNE
    return (unsigned short)(r >> 16);
}

// ---------------------------------------------------------------------------
// Pack kernel: P[r][c] = (bf16(M*exp|W|) << 16) | bf16(exp|W|).
// Low half is now bf16 (not fp16) so the fused loop can drop it straight into
// an LDS A-fragment for the denominator MFMA with zero float math.
// e <= exp(5.8) ~ 330 fits bf16; denom rel-err ~0.4%/sqrt(2048) -> negligible.
// ---------------------------------------------------------------------------
__global__ __launch_bounds__(256) void pack_kernel(
    const float* __restrict__ M, const float* __restrict__ W,
    unsigned* __restrict__ P)
{
    const size_t i4 = ((size_t)blockIdx.x * 256 + threadIdx.x) * 4;
    const f32x4 m4 = __builtin_nontemporal_load((const f32x4*)(M + i4));
    const f32x4 w4 = __builtin_nontemporal_load((const f32x4*)(W + i4));
    u32x4 o;
    {
        const float e = __expf(fabsf(w4.x));
        o.x = ((unsigned)f2bf(m4.x * e) << 16) | (unsigned)f2bf(e);
    }
    {
        const float e = __expf(fabsf(w4.y));
        o.y = ((unsigned)f2bf(m4.y * e) << 16) | (unsigned)f2bf(e);
    }
    {
        const float e = __expf(fabsf(w4.z));
        o.z = ((unsigned)f2bf(m4.z * e) << 16) | (unsigned)f2bf(e);
    }
    {
        const float e = __expf(fabsf(w4.w));
        o.w = ((unsigned)f2bf(m4.w * e) << 16) | (unsigned)f2bf(e);
    }
    *(u32x4*)(P + i4) = o;
}

// ---------------------------------------------------------------------------
// Counting sort per batch (values < 4000). Ties in any order: the matmul is
// invariant to j-permutation.
// ---------------------------------------------------------------------------
__global__ __launch_bounds__(1024) void sort_kernel(
    const int* __restrict__ stk_ten,
    int* __restrict__ sval,
    int* __restrict__ spos)
{
    __shared__ int hist[4000];
    __shared__ int base[4000];
    __shared__ int wsum[16];
    const int b = blockIdx.x, t = threadIdx.x;
    const int lane = t & 63, wv = t >> 6;
    const int* idxb = stk_ten + b * N;

    for (int j = t; j < 4000; j += 1024) hist[j] = 0;
    __syncthreads();
    const int v0 = idxb[t], v1 = idxb[t + 1024];
    atomicAdd(&hist[v0], 1);
    atomicAdd(&hist[v1], 1);
    __syncthreads();

    // scan: thread owns bins 4t..4t+3
    int h[4], c[4], run = 0;
    #pragma unroll
    for (int i = 0; i < 4; ++i) {
        const int bi = 4 * t + i;
        h[i] = (bi < 4000) ? hist[bi] : 0;
        run += h[i];
        c[i] = run;
    }
    const int tsum = run;
    int incl = tsum;
    #pragma unroll
    for (int d = 1; d < 64; d <<= 1) {
        const int tmp = __shfl_up(incl, d, 64);
        if (lane >= d) incl += tmp;
    }
    if (lane == 63) wsum[wv] = incl;
    __syncthreads();
    if (t < 16) {
        const int v = wsum[t];
        int iv = v;
        #pragma unroll
        for (int d = 1; d < 16; d <<= 1) {
            const int tmp = __shfl_up(iv, d, 64);
            if (lane >= d) iv += tmp;
        }
        wsum[t] = iv - v;               // exclusive across waves
    }
    __syncthreads();
    const int ex = incl - tsum + wsum[wv];
    #pragma unroll
    for (int i = 0; i < 4; ++i) {
        const int bi = 4 * t + i;
        if (bi < 4000) base[bi] = ex + c[i] - h[i];
    }
    __syncthreads();
    for (int j = t; j < 4000; j += 1024) hist[j] = 0;
    __syncthreads();
    {
        const int p0 = base[v0] + atomicAdd(&hist[v0], 1);
        sval[b * N + p0] = v0; spos[b * N + p0] = t;
        const int p1 = base[v1] + atomicAdd(&hist[v1], 1);
        sval[b * N + p1] = v1; spos[b * N + p1] = t + 1024;
    }
}

// ---------------------------------------------------------------------------
// xT[b][d][j_sorted] = bf16(x[b][spos[j]][d]).  4 MB, L2-resident B operand.
// ---------------------------------------------------------------------------
__global__ __launch_bounds__(256) void xt_kernel(
    const float* __restrict__ x,
    const int* __restrict__ spos,
    unsigned short* __restrict__ xT)
{
    __shared__ float xs[TJ][129];
    __shared__ int sp_s[TJ];
    const int t  = threadIdx.x;
    const int b  = blockIdx.x >> 5;
    const int jt = blockIdx.x & 31;
    const int j0 = jt * TJ;
    if (t < TJ) sp_s[t] = spos[b * N + j0 + t];
    __syncthreads();
    const int tx = t & 31, ty = t >> 5;
    const float* xb = x + (size_t)b * N * D;
    #pragma unroll
    for (int p = 0; p < 8; ++p) {
        const int r = ty + 8 * p;
        const float* src = xb + (size_t)sp_s[r] * D;
        #pragma unroll
        for (int i = 0; i < 4; ++i)
            xs[r][tx + 32 * i] = src[tx + 32 * i];
    }
    __syncthreads();
    const int jp = t & 31, dd0 = t >> 5;
    unsigned short* xTb = xT + (size_t)b * D * N;
    #pragma unroll
    for (int q = 0; q < 16; ++q) {
        const int dd = dd0 + 8 * q;
        const unsigned lo = f2bf(xs[2 * jp][dd]);
        const unsigned hi = f2bf(xs[2 * jp + 1][dd]);
        *(unsigned*)(xTb + (size_t)dd * N + j0 + 2 * jp) = (hi << 16) | lo;
    }
}

// ---------------------------------------------------------------------------
// Fused kernel. Round-2 fixes (round-1 regression was the register squeeze:
// launch_bounds(256,4) let the allocator target 64 VGPR / 8 waves for a grid
// that only has 4 blocks/CU -> serialized the 16-wide gather prefetch):
//  - amdgpu_waves_per_eu(4,4): EXACT occupancy pin -> pressure target 128
//    unified regs; allocator keeps gv/gvn/bv fully live (16-wide MLP).
//  - rowbase[] forced to SGPRs via readfirstlane (wave-uniform) -> -16 VGPR.
//  - l_part[16] VGPRs eliminated: denominator computed by an extra MFMA
//    (A = bf16(e) fragment via second LDS buffer, B = ones) into 4 AGPRs.
//    Coef loop is now pure bit-ops; epilogue butterfly (96 shuffles) gone.
//  - Gather issue moved to loop TOP (oldest in vmcnt order, ahead of bv),
//    enabled by 2-deep index prefetch (cj for tile tt+2 in flight).
// ---------------------------------------------------------------------------
__global__ __launch_bounds__(256) __attribute__((amdgpu_waves_per_eu(4, 4)))
void fused_kernel(
    const unsigned short* __restrict__ xT,
    const int* __restrict__ stk_ten,
    const unsigned* __restrict__ P,
    const int* __restrict__ sval,
    const int* __restrict__ spos,
    float* __restrict__ out)
{
    __shared__ __align__(16) unsigned short cs[KQ][IT * 72];  // 9216 B coef
    __shared__ __align__(16) unsigned short es[KQ][IT * 72];  // 9216 B exp
    __shared__ float accs[IT][132];                           // 8448 B
    __shared__ float lbuf[KQ][IT];
    __shared__ int ri_s[IT];

    const int t    = threadIdx.x;
    const int lane = t & 63;
    const int w    = t >> 6;
    const int wg   = (blockIdx.x & 7) * 128 + (blockIdx.x >> 3);  // batch->XCD
    const int b    = wg >> 7;                    // 128 i-tiles per batch
    const int i0   = (wg & 127) * IT;

    if (t < IT) ri_s[t] = stk_ten[b * N + i0 + t];
    for (int z = t; z < IT * 132; z += 256) (&accs[0][0])[z] = 0.0f;
    __syncthreads();

    // wave-uniform row bases -> SGPRs
    unsigned rowbase[IT];
    #pragma unroll
    for (int m = 0; m < IT; ++m)
        rowbase[m] = (unsigned)__builtin_amdgcn_readfirstlane(ri_s[m]) * (unsigned)ST;

    const int* svb = sval + b * N;
    const int* spb = spos + b * N;
    const unsigned short* xTb = xT + (size_t)b * D * N;
    unsigned short* csw = &cs[w][0];
    unsigned short* esw = &es[w][0];

    f32x4 acc[8];
    #pragma unroll
    for (int nb = 0; nb < 8; ++nb)
        #pragma unroll
        for (int r = 0; r < 4; ++r) acc[nb][r] = 0.0f;
    f32x4 accl;
    #pragma unroll
    for (int r = 0; r < 4; ++r) accl[r] = 0.0f;

    bf16x8 onesv;
    #pragma unroll
    for (int k = 0; k < 8; ++k) onesv[k] = (short)0x3F80;   // bf16 1.0

    const int jbase = w * (TPW * TJ);
    const int brow  = lane & 15;
    const int bcol  = (lane >> 4) * 8;

    // prologue: tile 0 + tile 1 indices; tile 0 gathers in flight
    unsigned gv[IT];
    int cjn, pj, pjn;
    {
        const int c0 = svb[jbase + lane];
        pj  = spb[jbase + lane];
        cjn = svb[jbase + TJ + lane];
        pjn = spb[jbase + TJ + lane];
        #pragma unroll
        for (int m = 0; m < IT; ++m) gv[m] = P[rowbase[m] + (unsigned)c0];
    }

    for (int tt = 0; tt < TPW; ++tt) {
        const int j0 = jbase + tt * TJ;
        const int j2 = (tt + 2 < TPW) ? j0 + 2 * TJ : jbase;  // wrap: discarded

        // tile tt+1 gathers FIRST (oldest in vmcnt order; cjn already resident)
        unsigned gvn[IT];
        #pragma unroll
        for (int m = 0; m < IT; ++m) gvn[m] = P[rowbase[m] + (unsigned)cjn];

        // tile tt+2 indices (2-deep prefetch)
        const int cj2 = svb[j2 + lane];
        const int pj2 = spb[j2 + lane];

        // B(kc=0) loads
        uint4 bv[8];
        #pragma unroll
        for (int nb = 0; nb < 8; ++nb)
            bv[nb] = *(const uint4*)(xTb + (size_t)(nb * 16 + brow) * N + j0 + bcol);

        // coefficients for tile tt (pure bit-ops): hi=bf16(m*e), lo=bf16(e)
        #pragma unroll
        for (int m = 0; m < IT; ++m) {
            const unsigned u = gv[m];
            const bool diag = (pj == i0 + m);
            csw[m * 72 + lane] = diag ? (unsigned short)0      : (unsigned short)(u >> 16);
            esw[m * 72 + lane] = diag ? (unsigned short)0x3F80 : (unsigned short)(u & 0xFFFFu);
        }

        // A-fragments (same-wave LDS round-trip; lgkmcnt only, no barrier)
        const bf16x8 av0 = *(const bf16x8*)(csw + brow * 72 + bcol);
        const bf16x8 av1 = *(const bf16x8*)(csw + brow * 72 + 32 + bcol);
        const bf16x8 ae0 = *(const bf16x8*)(esw + brow * 72 + bcol);
        const bf16x8 ae1 = *(const bf16x8*)(esw + brow * 72 + 32 + bcol);

        #pragma unroll
        for (int nb = 0; nb < 8; ++nb)
            acc[nb] = __builtin_amdgcn_mfma_f32_16x16x32_bf16(
                av0, *(const bf16x8*)&bv[nb], acc[nb], 0, 0, 0);
        accl = __builtin_amdgcn_mfma_f32_16x16x32_bf16(ae0, onesv, accl, 0, 0, 0);

        #pragma unroll
        for (int nb = 0; nb < 8; ++nb)
            bv[nb] = *(const uint4*)(xTb + (size_t)(nb * 16 + brow) * N + j0 + 32 + bcol);
        #pragma unroll
        for (int nb = 0; nb < 8; ++nb)
            acc[nb] = __builtin_amdgcn_mfma_f32_16x16x32_bf16(
                av1, *(const bf16x8*)&bv[nb], acc[nb], 0, 0, 0);
        accl = __builtin_amdgcn_mfma_f32_16x16x32_bf16(ae1, onesv, accl, 0, 0, 0);

        #pragma unroll
        for (int m = 0; m < IT; ++m) gv[m] = gvn[m];
        pj = pjn; cjn = cj2; pjn = pj2;
    }

    // epilogue: accl holds row sums (same value in every col); col 0 writes l
    if ((lane & 15) == 0) {
        #pragma unroll
        for (int r = 0; r < 4; ++r)
            lbuf[w][(lane >> 4) * 4 + r] = accl[r];
    }
    #pragma unroll
    for (int nb = 0; nb < 8; ++nb)
        #pragma unroll
        for (int r = 0; r < 4; ++r)
            atomicAdd(&accs[(lane >> 4) * 4 + r][nb * 16 + (lane & 15)], acc[nb][r]);
    __syncthreads();

    #pragma unroll
    for (int rr = 0; rr < 4; ++rr) {
        const int row = 4 * w + rr;
        const float linv = 1.0f /
            (lbuf[0][row] + lbuf[1][row] + lbuf[2][row] + lbuf[3][row]);
        #pragma unroll
        for (int p = 0; p < 2; ++p) {
            const int dd = lane + 64 * p;
            out[((size_t)(b * N + i0 + row) << 7) + dd] = accs[row][dd] * linv;
        }
    }
}

extern "C" void kernel_launch(void* const* d_in, const int* in_sizes, int n_in,
                              void* d_out, int out_size, void* d_ws, size_t ws_size,
                              hipStream_t stream) {
    const float* x          = (const float*)d_in[0];
    const int*   stk_ten    = (const int*)d_in[1];
    const float* stk_matrix = (const float*)d_in[2];
    const float* stk_weight = (const float*)d_in[3];
    float* out = (float*)d_out;

    unsigned* P = (unsigned*)d_ws;                              // 64 MB
    int* sval = (int*)(P + (size_t)ST * ST);                    // 64 KB
    int* spos = sval + BATCH * N;                               // 64 KB
    unsigned short* xT = (unsigned short*)(spos + BATCH * N);   // 4 MB

    pack_kernel<<<(ST * ST) / 1024, 256, 0, stream>>>(stk_matrix, stk_weight, P);
    sort_kernel<<<BATCH, 1024, 0, stream>>>(stk_ten, sval, spos);
    xt_kernel<<<BATCH * (N / TJ), 256, 0, stream>>>(x, spos, xT);
    fused_kernel<<<BATCH * (N / IT), 256, 0, stream>>>(
        xT, stk_ten, P, sval, spos, out);
}